// Round 20
// baseline (229.889 us; speedup 1.0000x reference)
//
#include <hip/hip_runtime.h>
#include <hip/hip_bf16.h>
#include <math.h>

#define BB 8
#define NN 200000
#define CC 81
#define TOPK 200
#define CAP 8192              // per-batch candidate capacity
#define FCAP 4096             // survivor capacity
#define NBIN 4096
#define THKEY 0x3E800000u     // bits of 0.25f (validated on this data by R13/R19)

static __device__ __forceinline__ int bin_of(unsigned key) {
    return (int)((key >> 14) & (NBIN - 1));
}

// ---------------------------------------------------------------------------
// Kernel Z: zero the 8 per-batch counters (each on its own 128B line).
// ---------------------------------------------------------------------------
__global__ __launch_bounds__(64) void zero_kernel(int* __restrict__ cnt) {
    if (threadIdx.x < BB) cnt[threadIdx.x * 32] = 0;
}

// ---------------------------------------------------------------------------
// Kernel A (unchanged from R19, passed): proven scores pipeline + two-phase
// candidate append (LDS collect -> ONE global RMW per non-empty block).
// ---------------------------------------------------------------------------
__global__ __launch_bounds__(256) void scores_kernel(const float* __restrict__ logits,
                                                     float* __restrict__ scores,
                                                     unsigned long long* __restrict__ cand,
                                                     int* __restrict__ cnt) {
    __shared__ float ls[64 * CC];     // 5184 floats = 20.7 KB
    __shared__ float lsc[64];
    __shared__ unsigned long long lbuf[64];
    __shared__ int s_app, s_base;
    int tid = threadIdx.x;
    int b = blockIdx.y;
    if (tid == 0) s_app = 0;
    size_t fbase = ((size_t)b * NN + (size_t)blockIdx.x * 64) * CC;  // 16B-aligned
    const float4* g4 = (const float4*)(logits + fbase);
    float4* l4 = (float4*)ls;

    int wbase = tid & ~63;            // wave-uniform base within block
#pragma unroll
    for (int k = 0; k < 5; ++k) {     // 5 full wave rounds = 1280 float4s
        __builtin_amdgcn_global_load_lds(
            (const __attribute__((address_space(1))) void*)(g4 + k * 256 + tid),
            (__attribute__((address_space(3))) void*)(l4 + k * 256 + wbase),
            16, 0, 0);
    }
    if (tid < 16) l4[1280 + tid] = g4[1280 + tid];   // tail 16 f4s, plain copy
    __syncthreads();                  // drains vmcnt incl. global_load_lds

    int r = tid >> 2;                 // row 0..63
    int q = tid & 3;                  // quarter
    const float* row = ls + r * CC;
    int head = (4 - (r & 3)) & 3;     // floats until 16B alignment (81r%4==r%4)
    int nf4 = (CC - head) >> 2;       // 19 or 20 aligned float4s
    int tail = CC - head - 4 * nf4;   // 0..3

    float m = -INFINITY, S = 0.0f;
    const float4* rp = (const float4*)(row + head);
    for (int j = q; j < nf4; j += 4) {
        float4 v = rp[j];
        m = fmaxf(fmaxf(fmaxf(m, v.x), v.y), fmaxf(v.z, v.w));
        S += __expf(v.x) + __expf(v.y) + __expf(v.z) + __expf(v.w);
    }
    if (q == 3) {
        for (int h2 = 0; h2 < head; ++h2) { float x = row[h2]; m = fmaxf(m, x); S += __expf(x); }
        for (int t2 = 0; t2 < tail; ++t2) { float x = row[CC - tail + t2]; m = fmaxf(m, x); S += __expf(x); }
    }
#pragma unroll
    for (int w = 1; w < 4; w <<= 1) {
        m = fmaxf(m, __shfl_xor(m, w, 64));
        S += __shfl_xor(S, w, 64);
    }
    if (q == 0) {
        float s = __expf(m) / S;
        lsc[r] = s;
        unsigned key = __float_as_uint(s);
        if (key >= THKEY) {
            int p = atomicAdd(&s_app, 1);        // LDS atomic, <=64 per block
            lbuf[p] = ((unsigned long long)key << 32) |
                      (unsigned)(blockIdx.x * 64 + r);
        }
    }
    __syncthreads();
    if (tid < 64) scores[(size_t)b * NN + (size_t)blockIdx.x * 64 + tid] = lsc[tid];
    int na = s_app;
    if (na > 0) {
        if (tid == 0) s_base = atomicAdd(&cnt[b * 32], na);   // ONE global RMW
        __syncthreads();
        if (tid < na) {
            int pos = s_base + tid;
            if (pos < CAP) cand[(size_t)b * CAP + pos] = lbuf[tid];
        }
    }
}

// ---------------------------------------------------------------------------
// Kernel F (unchanged from R19, passed). MEASUREMENT: launched TWICE this
// round; dur_us - 173.6 == F + K_final (idempotent: reads-only inputs).
// ---------------------------------------------------------------------------
__global__ __launch_bounds__(1024) void final_kernel(const float* __restrict__ scores,
                                                     const float* __restrict__ segs,
                                                     const unsigned long long* __restrict__ cand,
                                                     const int* __restrict__ cnt,
                                                     int* __restrict__ out) {
    __shared__ unsigned k_key[CAP];       // 32 KB
    __shared__ int k_idx[CAP];            // 32 KB
    __shared__ unsigned h[NBIN];          // 16 KB
    __shared__ unsigned csum[256];
    __shared__ int s_t, s_cnt;
    __shared__ unsigned fk[FCAP];         // 16 KB
    __shared__ int fi[FCAP];              // 16 KB
    __shared__ unsigned sel_k[TOPK];
    __shared__ int sel_i[TOPK];
    __shared__ int nms_i[TOPK];
    __shared__ float nms_x1[TOPK + 56], nms_x2[TOPK + 56];

    int b = blockIdx.x;
    int tid = threadIdx.x;
    const float* sc = scores + (size_t)b * NN;
    const float* sg = segs + (size_t)b * NN * 2;

    for (int i = tid; i < TOPK; i += 1024) {
        out[b * TOPK + i] = 0;
        out[(BB + b) * TOPK + i] = 0;
    }
    for (int i = tid; i < 56; i += 1024) { nms_x1[TOPK + i] = 0.f; nms_x2[TOPK + i] = 0.f; }

    int c = cnt[b * 32];
    int M;
    if (c >= TOPK && c <= CAP) {
        M = c;
        for (int j = tid; j < M; j += 1024) {
            unsigned long long p = cand[(size_t)b * CAP + j];
            k_key[j] = (unsigned)(p >> 32);
            k_idx[j] = (int)(p & 0xffffffffull);
        }
        __syncthreads();
    } else {
        for (int i = tid; i < NBIN; i += 1024) h[i] = 0u;
        if (tid == 0) s_cnt = 0;
        __syncthreads();
        const float4* sc4 = (const float4*)sc;
        for (int i = tid; i < NN / 4; i += 1024) {
            float4 v = sc4[i];
            atomicAdd(&h[bin_of(__float_as_uint(v.x))], 1u);
            atomicAdd(&h[bin_of(__float_as_uint(v.y))], 1u);
            atomicAdd(&h[bin_of(__float_as_uint(v.z))], 1u);
            atomicAdd(&h[bin_of(__float_as_uint(v.w))], 1u);
        }
        __syncthreads();
        unsigned s = 0;
        int hi = 0;
        if (tid < 256) {
            hi = NBIN - 1 - 16 * tid;
#pragma unroll
            for (int j = 0; j < 16; ++j) s += h[hi - j];
            csum[tid] = s;
        }
        __syncthreads();
        if (tid == 0) {
            unsigned run = 0;
            for (int t = 0; t < 256; ++t) { unsigned tmp = csum[t]; csum[t] = run; run += tmp; }
        }
        __syncthreads();
        if (tid < 256) {
            unsigned before = csum[tid];
            if (before < TOPK && before + s >= TOPK) {
                unsigned cum = before;
                for (int j = 0; j < 16; ++j) {
                    cum += h[hi - j];
                    if (cum >= TOPK) { s_t = hi - j; break; }
                }
            }
        }
        __syncthreads();
        int t = s_t;
        for (int i = tid; i < NN / 4; i += 1024) {
            const float4* sc4b = (const float4*)sc;
            float4 v = sc4b[i];
            unsigned keys[4] = { __float_as_uint(v.x), __float_as_uint(v.y),
                                 __float_as_uint(v.z), __float_as_uint(v.w) };
#pragma unroll
            for (int j = 0; j < 4; ++j) {
                if (bin_of(keys[j]) >= t) {
                    int pos = atomicAdd(&s_cnt, 1);
                    if (pos < CAP) { k_key[pos] = keys[j]; k_idx[pos] = 4 * i + j; }
                }
            }
        }
        __syncthreads();
        M = s_cnt; if (M > CAP) M = CAP;
    }

    for (int i = tid; i < NBIN; i += 1024) h[i] = 0u;
    if (tid == 0) s_cnt = 0;
    __syncthreads();
    for (int j = tid; j < M; j += 1024) atomicAdd(&h[bin_of(k_key[j])], 1u);
    __syncthreads();
    unsigned s2 = 0;
    int hi2 = 0;
    if (tid < 256) {
        hi2 = NBIN - 1 - 16 * tid;
#pragma unroll
        for (int j = 0; j < 16; ++j) s2 += h[hi2 - j];
        csum[tid] = s2;
    }
    __syncthreads();
    if (tid == 0) {
        unsigned run = 0;
        for (int t = 0; t < 256; ++t) { unsigned tmp = csum[t]; csum[t] = run; run += tmp; }
    }
    __syncthreads();
    if (tid < 256) {
        unsigned before = csum[tid];
        if (before < TOPK && before + s2 >= TOPK) {
            unsigned cum = before;
            for (int j = 0; j < 16; ++j) {
                cum += h[hi2 - j];
                if (cum >= TOPK) { s_t = hi2 - j; break; }
            }
        }
    }
    __syncthreads();
    int t2 = s_t;

    for (int j = tid; j < M; j += 1024) {
        if (bin_of(k_key[j]) >= t2) {
            int p = atomicAdd(&s_cnt, 1);
            if (p < FCAP) { fk[p] = k_key[j]; fi[p] = k_idx[j]; }
        }
    }
    __syncthreads();
    int M2 = s_cnt; if (M2 > FCAP) M2 = FCAP;

    for (int j = tid; j < M2; j += 1024) {
        unsigned kj = fk[j];
        int ij = fi[j];
        int rank = 0;
        for (int mm = 0; mm < M2; ++mm) {
            unsigned km = fk[mm];
            rank += (km > kj) || (km == kj && fi[mm] > ij);
        }
        if (rank < TOPK) { sel_k[rank] = kj; sel_i[rank] = ij; }
    }
    __syncthreads();

    if (tid < TOPK) {
        unsigned kj = sel_k[tid];
        int ij = sel_i[tid];
        int r2 = 0;
        for (int mm = 0; mm < TOPK; ++mm) {
            unsigned km = sel_k[mm];
            r2 += (km > kj) || (km == kj && sel_i[mm] < ij);
        }
        nms_i[r2] = ij;
        nms_x1[r2] = sg[2 * (size_t)ij];
        nms_x2[r2] = sg[2 * (size_t)ij + 1];
    }
    __syncthreads();

    if (tid >= 64) return;
    int lane = tid;
    float rx1[4], rx2[4];
#pragma unroll
    for (int k = 0; k < 4; ++k) {
        rx1[k] = nms_x1[k * 64 + lane];
        rx2[k] = nms_x2[k * 64 + lane];
    }
    unsigned long long m0 = ~0ull, m1 = ~0ull, m2 = ~0ull, m3 = 0xffull;

    int* keep = out + b * TOPK;
    for (int it = 0; it < TOPK; ++it) {
        int p;
        if (m0)      p = __ffsll(m0) - 1;
        else if (m1) p = 64 + __ffsll(m1) - 1;
        else if (m2) p = 128 + __ffsll(m2) - 1;
        else if (m3) p = 192 + __ffsll(m3) - 1;
        else break;

        float wx1 = nms_x1[p];
        float wx2 = nms_x2[p];
        if (lane == 0) keep[it] = nms_i[p];

        unsigned long long mw[4] = { m0, m1, m2, m3 };
        unsigned long long nm[4];
#pragma unroll
        for (int k = 0; k < 4; ++k) {
            bool alive = (mw[k] >> lane) & 1ull;
            bool kill = false;
            if (alive) {
                int pos = k * 64 + lane;
                if (pos == p) kill = true;
                else {
                    float inter = fminf(rx2[k], wx2) - fmaxf(rx1[k], wx1);
                    kill = inter > 0.f;
                }
            }
            nm[k] = __ballot(alive && !kill);
        }
        m0 = nm[0]; m1 = nm[1]; m2 = nm[2]; m3 = nm[3];
    }
}

extern "C" void kernel_launch(void* const* d_in, const int* in_sizes, int n_in,
                              void* d_out, int out_size, void* d_ws, size_t ws_size,
                              hipStream_t stream) {
    const float* logits = (const float*)d_in[0];   // (8, 200000, 81) f32
    const float* segs   = (const float*)d_in[1];   // (8, 200000, 2)  f32
    int* out = (int*)d_out;                        // (16, 200) int32

    char* ws = (char*)d_ws;
    float*              scores = (float*)ws;                            // 6,400,000 B
    unsigned long long* cand   = (unsigned long long*)(ws + 6400000);   // 524,288 B
    int*                cnt    = (int*)(ws + 6400000 + 524288);         // 8 lines (1 KB)

    zero_kernel<<<1, 64, 0, stream>>>(cnt);
    dim3 sgrid(NN / 64, BB);                       // 3125 x 8
    scores_kernel<<<sgrid, 256, 0, stream>>>(logits, scores, cand, cnt);
    // MEASUREMENT: final launched twice (idempotent). dur_us - 173.6 = F + K_f.
    final_kernel<<<BB, 1024, 0, stream>>>(scores, segs, cand, cnt, out);
    final_kernel<<<BB, 1024, 0, stream>>>(scores, segs, cand, cnt, out);
}

// Round 21
// 216.690 us; speedup vs baseline: 1.0609x; 1.0609x over previous
//
#include <hip/hip_runtime.h>
#include <hip/hip_bf16.h>
#include <math.h>

#define BB 8
#define NN 200000
#define CC 81
#define TOPK 200
#define CAP 4096              // per-batch candidate capacity (typ. M~780)
#define NBIN 4096
#define THKEY 0x3E800000u     // bits of 0.25f (validated on this data R13/R19)

static __device__ __forceinline__ int bin_of(unsigned key) {
    return (int)((key >> 14) & (NBIN - 1));
}

// ---------------------------------------------------------------------------
// Kernel Z: zero the 8 per-batch counters (each on its own 128B line).
// ---------------------------------------------------------------------------
__global__ __launch_bounds__(64) void zero_kernel(int* __restrict__ cnt) {
    if (threadIdx.x < BB) cnt[threadIdx.x * 32] = 0;
}

// ---------------------------------------------------------------------------
// Kernel A (unchanged from R19, passed): proven scores pipeline + two-phase
// candidate append (LDS collect -> ONE global RMW per non-empty block).
// ---------------------------------------------------------------------------
__global__ __launch_bounds__(256) void scores_kernel(const float* __restrict__ logits,
                                                     float* __restrict__ scores,
                                                     unsigned long long* __restrict__ cand,
                                                     int* __restrict__ cnt) {
    __shared__ float ls[64 * CC];     // 5184 floats = 20.7 KB
    __shared__ float lsc[64];
    __shared__ unsigned long long lbuf[64];
    __shared__ int s_app, s_base;
    int tid = threadIdx.x;
    int b = blockIdx.y;
    if (tid == 0) s_app = 0;
    size_t fbase = ((size_t)b * NN + (size_t)blockIdx.x * 64) * CC;  // 16B-aligned
    const float4* g4 = (const float4*)(logits + fbase);
    float4* l4 = (float4*)ls;

    int wbase = tid & ~63;            // wave-uniform base within block
#pragma unroll
    for (int k = 0; k < 5; ++k) {     // 5 full wave rounds = 1280 float4s
        __builtin_amdgcn_global_load_lds(
            (const __attribute__((address_space(1))) void*)(g4 + k * 256 + tid),
            (__attribute__((address_space(3))) void*)(l4 + k * 256 + wbase),
            16, 0, 0);
    }
    if (tid < 16) l4[1280 + tid] = g4[1280 + tid];   // tail 16 f4s, plain copy
    __syncthreads();                  // drains vmcnt incl. global_load_lds

    int r = tid >> 2;                 // row 0..63
    int q = tid & 3;                  // quarter
    const float* row = ls + r * CC;
    int head = (4 - (r & 3)) & 3;     // floats until 16B alignment (81r%4==r%4)
    int nf4 = (CC - head) >> 2;       // 19 or 20 aligned float4s
    int tail = CC - head - 4 * nf4;   // 0..3

    float m = -INFINITY, S = 0.0f;
    const float4* rp = (const float4*)(row + head);
    for (int j = q; j < nf4; j += 4) {
        float4 v = rp[j];
        m = fmaxf(fmaxf(fmaxf(m, v.x), v.y), fmaxf(v.z, v.w));
        S += __expf(v.x) + __expf(v.y) + __expf(v.z) + __expf(v.w);
    }
    if (q == 3) {
        for (int h2 = 0; h2 < head; ++h2) { float x = row[h2]; m = fmaxf(m, x); S += __expf(x); }
        for (int t2 = 0; t2 < tail; ++t2) { float x = row[CC - tail + t2]; m = fmaxf(m, x); S += __expf(x); }
    }
#pragma unroll
    for (int w = 1; w < 4; w <<= 1) {
        m = fmaxf(m, __shfl_xor(m, w, 64));
        S += __shfl_xor(S, w, 64);
    }
    if (q == 0) {
        float s = __expf(m) / S;
        lsc[r] = s;
        unsigned key = __float_as_uint(s);
        if (key >= THKEY) {
            int p = atomicAdd(&s_app, 1);        // LDS atomic, <=64 per block
            lbuf[p] = ((unsigned long long)key << 32) |
                      (unsigned)(blockIdx.x * 64 + r);
        }
    }
    __syncthreads();
    if (tid < 64) scores[(size_t)b * NN + (size_t)blockIdx.x * 64 + tid] = lsc[tid];
    int na = s_app;
    if (na > 0) {
        if (tid == 0) s_base = atomicAdd(&cnt[b * 32], na);   // ONE global RMW
        __syncthreads();
        if (tid < na) {
            int pos = s_base + tid;
            if (pos < CAP) cand[(size_t)b * CAP + pos] = lbuf[tid];
        }
    }
}

// ---------------------------------------------------------------------------
// Kernel F (v4): latency-chain-free common path.
//  FAST (200<=c<=CAP): direct exact rank over M packed u64 candidates.
//    Packed compare (key<<32)|idx == lex (key desc, idx desc) rank;
//    inner loop reads ulonglong2 (b128) with unroll 4 -> pipelined loads.
//  SLOW (else): proven full-scan hist+threshold+gather -> same direct rank.
//  Then: NMS-order re-rank via (key<<32)|~idx packed compare; mask-scan NMS
//  with float2-packed box reads (one b64 broadcast per iteration).
// ---------------------------------------------------------------------------
__global__ __launch_bounds__(1024) void final_kernel(const float* __restrict__ scores,
                                                     const float* __restrict__ segs,
                                                     const unsigned long long* __restrict__ cand,
                                                     const int* __restrict__ cnt,
                                                     int* __restrict__ out) {
    __shared__ __align__(16) unsigned long long ckey[CAP + 2];  // 32.8 KB
    __shared__ unsigned h[NBIN];                                // 16 KB (slow path)
    __shared__ unsigned csum[256];
    __shared__ int s_t, s_cnt;
    __shared__ __align__(16) unsigned long long sel[TOPK];
    __shared__ __align__(16) unsigned long long pk2[TOPK];
    __shared__ int nms_i[256];
    __shared__ float2 nms_xy[256];

    int b = blockIdx.x;
    int tid = threadIdx.x;
    const float* sc = scores + (size_t)b * NN;
    const float* sg = segs + (size_t)b * NN * 2;

    for (int i = tid; i < TOPK; i += 1024) {
        out[b * TOPK + i] = 0;
        out[(BB + b) * TOPK + i] = 0;
    }
    if (tid >= TOPK && tid < 256) { nms_xy[tid] = make_float2(0.f, 0.f); nms_i[tid] = 0; }

    int c = cnt[b * 32];
    int M;
    if (c >= TOPK && c <= CAP) {
        // ---- FAST: load packed candidates straight into LDS ----
        M = c;
        for (int j = tid; j < M; j += 1024) ckey[j] = cand[(size_t)b * CAP + j];
    } else {
        // ---- SLOW: full hist + threshold + gather from scores (proven) ----
        for (int i = tid; i < NBIN; i += 1024) h[i] = 0u;
        if (tid == 0) s_cnt = 0;
        __syncthreads();
        const float4* sc4 = (const float4*)sc;
        for (int i = tid; i < NN / 4; i += 1024) {
            float4 v = sc4[i];
            atomicAdd(&h[bin_of(__float_as_uint(v.x))], 1u);
            atomicAdd(&h[bin_of(__float_as_uint(v.y))], 1u);
            atomicAdd(&h[bin_of(__float_as_uint(v.z))], 1u);
            atomicAdd(&h[bin_of(__float_as_uint(v.w))], 1u);
        }
        __syncthreads();
        unsigned s = 0;
        int hi = 0;
        if (tid < 256) {
            hi = NBIN - 1 - 16 * tid;
#pragma unroll
            for (int j = 0; j < 16; ++j) s += h[hi - j];
            csum[tid] = s;
        }
        __syncthreads();
        if (tid == 0) {
            unsigned run = 0;
            for (int t = 0; t < 256; ++t) { unsigned tmp = csum[t]; csum[t] = run; run += tmp; }
        }
        __syncthreads();
        if (tid < 256) {
            unsigned before = csum[tid];
            if (before < TOPK && before + s >= TOPK) {
                unsigned cum = before;
                for (int j = 0; j < 16; ++j) {
                    cum += h[hi - j];
                    if (cum >= TOPK) { s_t = hi - j; break; }
                }
            }
        }
        __syncthreads();
        int t = s_t;
        for (int i = tid; i < NN / 4; i += 1024) {
            float4 v = sc4[i];
            unsigned keys[4] = { __float_as_uint(v.x), __float_as_uint(v.y),
                                 __float_as_uint(v.z), __float_as_uint(v.w) };
#pragma unroll
            for (int j = 0; j < 4; ++j) {
                if (bin_of(keys[j]) >= t) {
                    int pos = atomicAdd(&s_cnt, 1);
                    if (pos < CAP)
                        ckey[pos] = ((unsigned long long)keys[j] << 32) |
                                    (unsigned)(4 * i + j);
                }
            }
        }
        __syncthreads();
        M = s_cnt; if (M > CAP) M = CAP;
    }
    if (tid == 0) { ckey[M] = 0ull; ckey[M + 1] = 0ull; }   // pad for b128 reads
    __syncthreads();

    // ---- direct exact rank by (key desc, idx desc): packed u64 compare ----
    {
        int Mh = (M + 1) >> 1;                       // ulonglong2 count (covers pad)
        const ulonglong2* c2 = (const ulonglong2*)ckey;
        for (int j = tid; j < M; j += 1024) {
            unsigned long long pj = ckey[j];
            int rank = 0;
#pragma unroll 4
            for (int mm = 0; mm < Mh; ++mm) {
                ulonglong2 v = c2[mm];
                rank += (v.x > pj) + (v.y > pj);     // 0-pad never counts
            }
            if (rank < TOPK) sel[rank] = pj;
        }
    }
    __syncthreads();

    // ---- NMS-order re-rank: packed (key<<32)|~idx == (key desc, idx asc) ----
    if (tid < TOPK) {
        unsigned long long p = sel[tid];
        pk2[tid] = (p & 0xffffffff00000000ull) | (unsigned)(~(unsigned)p);
    }
    __syncthreads();
    if (tid < TOPK) {
        unsigned long long pj = pk2[tid];
        int r2 = 0;
        const ulonglong2* p2 = (const ulonglong2*)pk2;
#pragma unroll 4
        for (int mm = 0; mm < TOPK / 2; ++mm) {
            ulonglong2 v = p2[mm];
            r2 += (v.x > pj) + (v.y > pj);
        }
        int idx = (int)(~(unsigned)pj);
        nms_i[r2] = idx;
        nms_xy[r2] = make_float2(sg[2 * (size_t)idx], sg[2 * (size_t)idx + 1]);
    }
    __syncthreads();

    // ---- mask-scan greedy NMS on wave 0 (one b64 broadcast per iter) ----
    if (tid >= 64) return;
    int lane = tid;
    float2 rxy[4];
#pragma unroll
    for (int k = 0; k < 4; ++k) rxy[k] = nms_xy[k * 64 + lane];
    unsigned long long m0 = ~0ull, m1 = ~0ull, m2 = ~0ull, m3 = 0xffull;

    int* keep = out + b * TOPK;
    for (int it = 0; it < TOPK; ++it) {
        int p;
        if (m0)      p = __ffsll(m0) - 1;
        else if (m1) p = 64 + __ffsll(m1) - 1;
        else if (m2) p = 128 + __ffsll(m2) - 1;
        else if (m3) p = 192 + __ffsll(m3) - 1;
        else break;

        float2 w = nms_xy[p];                       // single uniform b64 read
        if (lane == 0) keep[it] = nms_i[p];

        unsigned long long mw[4] = { m0, m1, m2, m3 };
        unsigned long long nm[4];
#pragma unroll
        for (int k = 0; k < 4; ++k) {
            bool alive = (mw[k] >> lane) & 1ull;
            bool kill = false;
            if (alive) {
                int pos = k * 64 + lane;
                if (pos == p) kill = true;
                else {
                    float inter = fminf(rxy[k].y, w.y) - fmaxf(rxy[k].x, w.x);
                    kill = inter > 0.f;
                }
            }
            nm[k] = __ballot(alive && !kill);
        }
        m0 = nm[0]; m1 = nm[1]; m2 = nm[2]; m3 = nm[3];
    }
}

extern "C" void kernel_launch(void* const* d_in, const int* in_sizes, int n_in,
                              void* d_out, int out_size, void* d_ws, size_t ws_size,
                              hipStream_t stream) {
    const float* logits = (const float*)d_in[0];   // (8, 200000, 81) f32
    const float* segs   = (const float*)d_in[1];   // (8, 200000, 2)  f32
    int* out = (int*)d_out;                        // (16, 200) int32

    char* ws = (char*)d_ws;
    float*              scores = (float*)ws;                            // 6,400,000 B
    unsigned long long* cand   = (unsigned long long*)(ws + 6400000);   // 8*4096*8 = 262,144 B
    int*                cnt    = (int*)(ws + 6400000 + 262144);         // 8 lines (1 KB)

    zero_kernel<<<1, 64, 0, stream>>>(cnt);
    dim3 sgrid(NN / 64, BB);                       // 3125 x 8
    scores_kernel<<<sgrid, 256, 0, stream>>>(logits, scores, cand, cnt);
    final_kernel<<<BB, 1024, 0, stream>>>(scores, segs, cand, cnt, out);
}

// Round 22
// 167.785 us; speedup vs baseline: 1.3701x; 1.2915x over previous
//
#include <hip/hip_runtime.h>
#include <hip/hip_bf16.h>
#include <math.h>

#define BB 8
#define NN 200000
#define CC 81
#define TOPK 200
#define CAP 8192              // per-batch candidate capacity
#define SVCAP 2048            // survivor capacity (typ. ~210)
#define NBIN 4096
#define THKEY 0x3E800000u     // bits of 0.25f (prefilter threshold)

static __device__ __forceinline__ int bin_of(unsigned key) {
    return (int)((key >> 14) & (NBIN - 1));
}

// ---------------------------------------------------------------------------
// Kernel Z: zero the 8 per-batch counters (each on its own 128B line).
// ---------------------------------------------------------------------------
__global__ __launch_bounds__(64) void zero_kernel(int* __restrict__ cnt) {
    if (threadIdx.x < BB) cnt[threadIdx.x * 32] = 0;
}

// ---------------------------------------------------------------------------
// Kernel A (unchanged from R19, passed 3x): proven scores pipeline + two-phase
// candidate append (LDS collect -> ONE global RMW per non-empty block).
// ---------------------------------------------------------------------------
__global__ __launch_bounds__(256) void scores_kernel(const float* __restrict__ logits,
                                                     float* __restrict__ scores,
                                                     unsigned long long* __restrict__ cand,
                                                     int* __restrict__ cnt) {
    __shared__ float ls[64 * CC];     // 5184 floats = 20.7 KB
    __shared__ float lsc[64];
    __shared__ unsigned long long lbuf[64];
    __shared__ int s_app, s_base;
    int tid = threadIdx.x;
    int b = blockIdx.y;
    if (tid == 0) s_app = 0;
    size_t fbase = ((size_t)b * NN + (size_t)blockIdx.x * 64) * CC;  // 16B-aligned
    const float4* g4 = (const float4*)(logits + fbase);
    float4* l4 = (float4*)ls;

    int wbase = tid & ~63;            // wave-uniform base within block
#pragma unroll
    for (int k = 0; k < 5; ++k) {     // 5 full wave rounds = 1280 float4s
        __builtin_amdgcn_global_load_lds(
            (const __attribute__((address_space(1))) void*)(g4 + k * 256 + tid),
            (__attribute__((address_space(3))) void*)(l4 + k * 256 + wbase),
            16, 0, 0);
    }
    if (tid < 16) l4[1280 + tid] = g4[1280 + tid];   // tail 16 f4s, plain copy
    __syncthreads();                  // drains vmcnt incl. global_load_lds

    int r = tid >> 2;                 // row 0..63
    int q = tid & 3;                  // quarter
    const float* row = ls + r * CC;
    int head = (4 - (r & 3)) & 3;     // floats until 16B alignment (81r%4==r%4)
    int nf4 = (CC - head) >> 2;       // 19 or 20 aligned float4s
    int tail = CC - head - 4 * nf4;   // 0..3

    float m = -INFINITY, S = 0.0f;
    const float4* rp = (const float4*)(row + head);
    for (int j = q; j < nf4; j += 4) {
        float4 v = rp[j];
        m = fmaxf(fmaxf(fmaxf(m, v.x), v.y), fmaxf(v.z, v.w));
        S += __expf(v.x) + __expf(v.y) + __expf(v.z) + __expf(v.w);
    }
    if (q == 3) {
        for (int h2 = 0; h2 < head; ++h2) { float x = row[h2]; m = fmaxf(m, x); S += __expf(x); }
        for (int t2 = 0; t2 < tail; ++t2) { float x = row[CC - tail + t2]; m = fmaxf(m, x); S += __expf(x); }
    }
#pragma unroll
    for (int w = 1; w < 4; w <<= 1) {
        m = fmaxf(m, __shfl_xor(m, w, 64));
        S += __shfl_xor(S, w, 64);
    }
    if (q == 0) {
        float s = __expf(m) / S;
        lsc[r] = s;
        unsigned key = __float_as_uint(s);
        if (key >= THKEY) {
            int p = atomicAdd(&s_app, 1);        // LDS atomic, <=64 per block
            lbuf[p] = ((unsigned long long)key << 32) |
                      (unsigned)(blockIdx.x * 64 + r);
        }
    }
    __syncthreads();
    if (tid < 64) scores[(size_t)b * NN + (size_t)blockIdx.x * 64 + tid] = lsc[tid];
    int na = s_app;
    if (na > 0) {
        if (tid == 0) s_base = atomicAdd(&cnt[b * 32], na);   // ONE global RMW
        __syncthreads();
        if (tid < na) {
            int pos = s_base + tid;
            if (pos < CAP) cand[(size_t)b * CAP + pos] = lbuf[tid];
        }
    }
}

// ---------------------------------------------------------------------------
// find exact rank-TOPK threshold bin of LDS hist h[NBIN], scanning from the
// top. WAVE-PARALLEL scan (shfl_up Kogge-Stone + wave totals) replacing the
// ~20us tid==0 serial 256-loop. All 1024 threads must call (uniform).
// ---------------------------------------------------------------------------
static __device__ __forceinline__ int rank_bin(unsigned* h, unsigned* wtot,
                                               int* s_t, int tid) {
    int lane = tid & 63, wv = tid >> 6;
    unsigned s = 0;
    int hi = NBIN - 1 - 16 * tid;
    if (tid < 256) {
#pragma unroll
        for (int j = 0; j < 16; ++j) s += h[hi - j];
    }
    unsigned inc = s;
#pragma unroll
    for (int d = 1; d < 64; d <<= 1) {
        unsigned o = __shfl_up(inc, d, 64);
        if (lane >= d) inc += o;
    }
    if (tid < 256 && lane == 63) wtot[wv] = inc;
    __syncthreads();
    if (tid < 256) {
        unsigned before = inc - s;
        for (int wp = 0; wp < wv; ++wp) before += wtot[wp];
        if (before < TOPK && before + s >= TOPK) {
            unsigned cum = before;
            for (int j = 0; j < 16; ++j) {
                cum += h[hi - j];
                if (cum >= TOPK) { *s_t = hi - j; break; }
            }
        }
    }
    __syncthreads();
    return *s_t;
}

// ---------------------------------------------------------------------------
// Kernel F (v5): CAP restored to 8192 (R21's 4096 likely overflowed -> slow
// path); prune-before-rank restored (R21's direct rank over all M was the
// other suspect). Candidate hist -> parallel-scan rank-200 bin -> ~210
// survivors -> packed-u64 vectorized rank/re-rank -> float2 mask-scan NMS.
// Slow path (c out of range): full-scan hist+gather feeds the same path.
// ---------------------------------------------------------------------------
__global__ __launch_bounds__(1024) void final_kernel(const float* __restrict__ scores,
                                                     const float* __restrict__ segs,
                                                     const unsigned long long* __restrict__ cand,
                                                     const int* __restrict__ cnt,
                                                     int* __restrict__ out) {
    __shared__ __align__(16) unsigned long long ckey[CAP + 2];   // 65.6 KB
    __shared__ unsigned h[NBIN];                                 // 16 KB
    __shared__ unsigned wtot[4];
    __shared__ int s_t, s_cnt;
    __shared__ __align__(16) unsigned long long sv[SVCAP + 2];   // 16.4 KB
    __shared__ __align__(16) unsigned long long sel[TOPK];
    __shared__ __align__(16) unsigned long long pk2[TOPK];
    __shared__ int nms_i[256];
    __shared__ float2 nms_xy[256];

    int b = blockIdx.x;
    int tid = threadIdx.x;
    const float* sc = scores + (size_t)b * NN;
    const float* sg = segs + (size_t)b * NN * 2;

    for (int i = tid; i < TOPK; i += 1024) {
        out[b * TOPK + i] = 0;
        out[(BB + b) * TOPK + i] = 0;
    }
    if (tid >= TOPK && tid < 256) { nms_xy[tid] = make_float2(0.f, 0.f); nms_i[tid] = 0; }

    int c = cnt[b * 32];
    int M;
    if (c >= TOPK && c <= CAP) {
        // ---- FAST: load packed candidates straight into LDS ----
        M = c;
        for (int j = tid; j < M; j += 1024) ckey[j] = cand[(size_t)b * CAP + j];
        __syncthreads();
    } else {
        // ---- SLOW: full hist + threshold + gather from scores (proven) ----
        for (int i = tid; i < NBIN; i += 1024) h[i] = 0u;
        if (tid == 0) s_cnt = 0;
        __syncthreads();
        const float4* sc4 = (const float4*)sc;
        for (int i = tid; i < NN / 4; i += 1024) {
            float4 v = sc4[i];
            atomicAdd(&h[bin_of(__float_as_uint(v.x))], 1u);
            atomicAdd(&h[bin_of(__float_as_uint(v.y))], 1u);
            atomicAdd(&h[bin_of(__float_as_uint(v.z))], 1u);
            atomicAdd(&h[bin_of(__float_as_uint(v.w))], 1u);
        }
        __syncthreads();
        int t = rank_bin(h, wtot, &s_t, tid);
        for (int i = tid; i < NN / 4; i += 1024) {
            float4 v = sc4[i];
            unsigned keys[4] = { __float_as_uint(v.x), __float_as_uint(v.y),
                                 __float_as_uint(v.z), __float_as_uint(v.w) };
#pragma unroll
            for (int j = 0; j < 4; ++j) {
                if (bin_of(keys[j]) >= t) {
                    int pos = atomicAdd(&s_cnt, 1);
                    if (pos < CAP)
                        ckey[pos] = ((unsigned long long)keys[j] << 32) |
                                    (unsigned)(4 * i + j);
                }
            }
        }
        __syncthreads();
        M = s_cnt; if (M > CAP) M = CAP;
    }

    // ---- candidate hist -> exact rank-200 threshold bin (parallel scan) ----
    for (int i = tid; i < NBIN; i += 1024) h[i] = 0u;
    if (tid == 0) s_cnt = 0;
    __syncthreads();
    for (int j = tid; j < M; j += 1024)
        atomicAdd(&h[bin_of((unsigned)(ckey[j] >> 32))], 1u);
    __syncthreads();
    int t2 = rank_bin(h, wtot, &s_t, tid);

    // ---- survivors (bin >= t2): ~210 expected ----
    for (int j = tid; j < M; j += 1024) {
        unsigned long long p = ckey[j];
        if (bin_of((unsigned)(p >> 32)) >= t2) {
            int q = atomicAdd(&s_cnt, 1);
            if (q < SVCAP) sv[q] = p;
        }
    }
    __syncthreads();
    int M2 = s_cnt; if (M2 > SVCAP) M2 = SVCAP;
    if (tid == 0) { sv[M2] = 0ull; sv[M2 + 1] = 0ull; }   // pad for b128 reads
    __syncthreads();

    // ---- exact rank by (key desc, idx desc): packed u64, b128 reads ----
    {
        int Mh = (M2 + 1) >> 1;
        const ulonglong2* v2 = (const ulonglong2*)sv;
        for (int j = tid; j < M2; j += 1024) {
            unsigned long long pj = sv[j];
            int rank = 0;
#pragma unroll 4
            for (int mm = 0; mm < Mh; ++mm) {
                ulonglong2 v = v2[mm];
                rank += (v.x > pj) + (v.y > pj);      // 0-pad never counts
            }
            if (rank < TOPK) sel[rank] = pj;
        }
    }
    __syncthreads();

    // ---- NMS-order re-rank: (key<<32)|~idx == (key desc, idx asc) ----
    if (tid < TOPK) {
        unsigned long long p = sel[tid];
        pk2[tid] = (p & 0xffffffff00000000ull) | (unsigned)(~(unsigned)p);
    }
    __syncthreads();
    if (tid < TOPK) {
        unsigned long long pj = pk2[tid];
        int r2 = 0;
        const ulonglong2* p2 = (const ulonglong2*)pk2;
#pragma unroll 4
        for (int mm = 0; mm < TOPK / 2; ++mm) {
            ulonglong2 v = p2[mm];
            r2 += (v.x > pj) + (v.y > pj);
        }
        int idx = (int)(~(unsigned)pj);
        nms_i[r2] = idx;
        nms_xy[r2] = make_float2(sg[2 * (size_t)idx], sg[2 * (size_t)idx + 1]);
    }
    __syncthreads();

    // ---- mask-scan greedy NMS on wave 0 (one b64 broadcast per iter) ----
    if (tid >= 64) return;
    int lane = tid;
    float2 rxy[4];
#pragma unroll
    for (int k = 0; k < 4; ++k) rxy[k] = nms_xy[k * 64 + lane];
    unsigned long long m0 = ~0ull, m1 = ~0ull, m2 = ~0ull, m3 = 0xffull;

    int* keep = out + b * TOPK;
    for (int it = 0; it < TOPK; ++it) {
        int p;
        if (m0)      p = __ffsll(m0) - 1;
        else if (m1) p = 64 + __ffsll(m1) - 1;
        else if (m2) p = 128 + __ffsll(m2) - 1;
        else if (m3) p = 192 + __ffsll(m3) - 1;
        else break;

        float2 w = nms_xy[p];                       // single uniform b64 read
        if (lane == 0) keep[it] = nms_i[p];

        unsigned long long mw[4] = { m0, m1, m2, m3 };
        unsigned long long nm[4];
#pragma unroll
        for (int k = 0; k < 4; ++k) {
            bool alive = (mw[k] >> lane) & 1ull;
            bool kill = false;
            if (alive) {
                int pos = k * 64 + lane;
                if (pos == p) kill = true;
                else {
                    float inter = fminf(rxy[k].y, w.y) - fmaxf(rxy[k].x, w.x);
                    kill = inter > 0.f;
                }
            }
            nm[k] = __ballot(alive && !kill);
        }
        m0 = nm[0]; m1 = nm[1]; m2 = nm[2]; m3 = nm[3];
    }
}

extern "C" void kernel_launch(void* const* d_in, const int* in_sizes, int n_in,
                              void* d_out, int out_size, void* d_ws, size_t ws_size,
                              hipStream_t stream) {
    const float* logits = (const float*)d_in[0];   // (8, 200000, 81) f32
    const float* segs   = (const float*)d_in[1];   // (8, 200000, 2)  f32
    int* out = (int*)d_out;                        // (16, 200) int32

    char* ws = (char*)d_ws;
    float*              scores = (float*)ws;                            // 6,400,000 B
    unsigned long long* cand   = (unsigned long long*)(ws + 6400000);   // 8*8192*8 = 524,288 B
    int*                cnt    = (int*)(ws + 6400000 + 524288);         // 8 lines (1 KB)

    zero_kernel<<<1, 64, 0, stream>>>(cnt);
    dim3 sgrid(NN / 64, BB);                       // 3125 x 8
    scores_kernel<<<sgrid, 256, 0, stream>>>(logits, scores, cand, cnt);
    final_kernel<<<BB, 1024, 0, stream>>>(scores, segs, cand, cnt, out);
}

// Round 23
// 145.127 us; speedup vs baseline: 1.5841x; 1.1561x over previous
//
#include <hip/hip_runtime.h>
#include <hip/hip_bf16.h>
#include <math.h>

#define BB 8
#define NN 200000
#define CC 81
#define TOPK 200
#define CAP 16384             // per-batch candidate capacity (true c ~5-8K)
#define SVCAP 2048            // survivor capacity (typ. ~210)
#define NBIN 4096
#define THKEY 0x3E800000u     // bits of 0.25f (prefilter threshold)

static __device__ __forceinline__ int bin_of(unsigned key) {
    return (int)((key >> 14) & (NBIN - 1));
}

// ---------------------------------------------------------------------------
// Kernel Z: zero the 8 per-batch counters (each on its own 128B line).
// ---------------------------------------------------------------------------
__global__ __launch_bounds__(64) void zero_kernel(int* __restrict__ cnt) {
    if (threadIdx.x < BB) cnt[threadIdx.x * 32] = 0;
}

// ---------------------------------------------------------------------------
// Kernel A (unchanged from R22, passed 4x): proven scores pipeline + two-phase
// candidate append (LDS collect -> ONE global RMW per non-empty block).
// ---------------------------------------------------------------------------
__global__ __launch_bounds__(256) void scores_kernel(const float* __restrict__ logits,
                                                     float* __restrict__ scores,
                                                     unsigned long long* __restrict__ cand,
                                                     int* __restrict__ cnt) {
    __shared__ float ls[64 * CC];     // 5184 floats = 20.7 KB
    __shared__ float lsc[64];
    __shared__ unsigned long long lbuf[64];
    __shared__ int s_app, s_base;
    int tid = threadIdx.x;
    int b = blockIdx.y;
    if (tid == 0) s_app = 0;
    size_t fbase = ((size_t)b * NN + (size_t)blockIdx.x * 64) * CC;  // 16B-aligned
    const float4* g4 = (const float4*)(logits + fbase);
    float4* l4 = (float4*)ls;

    int wbase = tid & ~63;            // wave-uniform base within block
#pragma unroll
    for (int k = 0; k < 5; ++k) {     // 5 full wave rounds = 1280 float4s
        __builtin_amdgcn_global_load_lds(
            (const __attribute__((address_space(1))) void*)(g4 + k * 256 + tid),
            (__attribute__((address_space(3))) void*)(l4 + k * 256 + wbase),
            16, 0, 0);
    }
    if (tid < 16) l4[1280 + tid] = g4[1280 + tid];   // tail 16 f4s, plain copy
    __syncthreads();                  // drains vmcnt incl. global_load_lds

    int r = tid >> 2;                 // row 0..63
    int q = tid & 3;                  // quarter
    const float* row = ls + r * CC;
    int head = (4 - (r & 3)) & 3;     // floats until 16B alignment (81r%4==r%4)
    int nf4 = (CC - head) >> 2;       // 19 or 20 aligned float4s
    int tail = CC - head - 4 * nf4;   // 0..3

    float m = -INFINITY, S = 0.0f;
    const float4* rp = (const float4*)(row + head);
    for (int j = q; j < nf4; j += 4) {
        float4 v = rp[j];
        m = fmaxf(fmaxf(fmaxf(m, v.x), v.y), fmaxf(v.z, v.w));
        S += __expf(v.x) + __expf(v.y) + __expf(v.z) + __expf(v.w);
    }
    if (q == 3) {
        for (int h2 = 0; h2 < head; ++h2) { float x = row[h2]; m = fmaxf(m, x); S += __expf(x); }
        for (int t2 = 0; t2 < tail; ++t2) { float x = row[CC - tail + t2]; m = fmaxf(m, x); S += __expf(x); }
    }
#pragma unroll
    for (int w = 1; w < 4; w <<= 1) {
        m = fmaxf(m, __shfl_xor(m, w, 64));
        S += __shfl_xor(S, w, 64);
    }
    if (q == 0) {
        float s = __expf(m) / S;
        lsc[r] = s;
        unsigned key = __float_as_uint(s);
        if (key >= THKEY) {
            int p = atomicAdd(&s_app, 1);        // LDS atomic, <=64 per block
            lbuf[p] = ((unsigned long long)key << 32) |
                      (unsigned)(blockIdx.x * 64 + r);
        }
    }
    __syncthreads();
    if (tid < 64) scores[(size_t)b * NN + (size_t)blockIdx.x * 64 + tid] = lsc[tid];
    int na = s_app;
    if (na > 0) {
        if (tid == 0) s_base = atomicAdd(&cnt[b * 32], na);   // ONE global RMW
        __syncthreads();
        if (tid < na) {
            int pos = s_base + tid;
            if (pos < CAP) cand[(size_t)b * CAP + pos] = lbuf[tid];
        }
    }
}

// ---------------------------------------------------------------------------
// rank_bin: exact rank-TOPK threshold bin of LDS hist h[NBIN], from the top.
// Wave-parallel scan (proven R22). All 1024 threads must call (uniform).
// ---------------------------------------------------------------------------
static __device__ __forceinline__ int rank_bin(unsigned* h, unsigned* wtot,
                                               int* s_t, int tid) {
    int lane = tid & 63, wv = tid >> 6;
    unsigned s = 0;
    int hi = NBIN - 1 - 16 * tid;
    if (tid < 256) {
#pragma unroll
        for (int j = 0; j < 16; ++j) s += h[hi - j];
    }
    unsigned inc = s;
#pragma unroll
    for (int d = 1; d < 64; d <<= 1) {
        unsigned o = __shfl_up(inc, d, 64);
        if (lane >= d) inc += o;
    }
    if (tid < 256 && lane == 63) wtot[wv] = inc;
    __syncthreads();
    if (tid < 256) {
        unsigned before = inc - s;
        for (int wp = 0; wp < wv; ++wp) before += wtot[wp];
        if (before < TOPK && before + s >= TOPK) {
            unsigned cum = before;
            for (int j = 0; j < 16; ++j) {
                cum += h[hi - j];
                if (cum >= TOPK) { *s_t = hi - j; break; }
            }
        }
    }
    __syncthreads();
    return *s_t;
}

// ---------------------------------------------------------------------------
// Kernel F (v6): candidates streamed from GLOBAL (L2-hot; no 65KB LDS stage);
// hist -> rank-200 bin -> ~210 survivors in LDS -> packed-u64 rank/re-rank ->
// PRECOMPUTED 200x200 kill matrix (parallel ballots) -> single-thread greedy
// scan (ffs + 4 independent b64 reads/iter; no per-iter FP or ballots).
// Slow path (c out of range): full-scan gather into cand, same common path.
// ---------------------------------------------------------------------------
__global__ __launch_bounds__(1024) void final_kernel(const float* __restrict__ scores,
                                                     const float* __restrict__ segs,
                                                     unsigned long long* __restrict__ cand,
                                                     const int* __restrict__ cnt,
                                                     int* __restrict__ out) {
    __shared__ unsigned h[NBIN];                                 // 16 KB
    __shared__ unsigned wtot[4];
    __shared__ int s_t, s_cnt;
    __shared__ __align__(16) unsigned long long sv[SVCAP + 2];   // 16.4 KB
    __shared__ __align__(16) unsigned long long sel[TOPK];
    __shared__ __align__(16) unsigned long long pk2[TOPK];
    __shared__ int nms_i[256];
    __shared__ float2 nms_xy[256];
    __shared__ __align__(32) unsigned long long krow[TOPK][4];   // 6.4 KB

    int b = blockIdx.x;
    int tid = threadIdx.x;
    const float* sc = scores + (size_t)b * NN;
    const float* sg = segs + (size_t)b * NN * 2;
    unsigned long long* cb = cand + (size_t)b * CAP;

    for (int i = tid; i < TOPK; i += 1024) {
        out[b * TOPK + i] = 0;
        out[(BB + b) * TOPK + i] = 0;
    }
    if (tid < 256) { nms_xy[tid] = make_float2(0.f, 0.f); nms_i[tid] = 0; }
    for (int i = tid; i < NBIN; i += 1024) h[i] = 0u;
    if (tid == 0) s_cnt = 0;
    __syncthreads();

    int c = cnt[b * 32];
    int M;
    if (c >= TOPK && c <= CAP) {
        M = c;                         // FAST: candidates already in cand
    } else {
        // SLOW: full-scan hist -> threshold -> gather into cand (ours to use)
        const float4* sc4 = (const float4*)sc;
        for (int i = tid; i < NN / 4; i += 1024) {
            float4 v = sc4[i];
            atomicAdd(&h[bin_of(__float_as_uint(v.x))], 1u);
            atomicAdd(&h[bin_of(__float_as_uint(v.y))], 1u);
            atomicAdd(&h[bin_of(__float_as_uint(v.z))], 1u);
            atomicAdd(&h[bin_of(__float_as_uint(v.w))], 1u);
        }
        __syncthreads();
        int t = rank_bin(h, wtot, &s_t, tid);
        for (int i = tid; i < NN / 4; i += 1024) {
            float4 v = sc4[i];
            unsigned keys[4] = { __float_as_uint(v.x), __float_as_uint(v.y),
                                 __float_as_uint(v.z), __float_as_uint(v.w) };
#pragma unroll
            for (int j = 0; j < 4; ++j) {
                if (bin_of(keys[j]) >= t) {
                    int pos = atomicAdd(&s_cnt, 1);   // LDS atomic
                    if (pos < CAP)
                        cb[pos] = ((unsigned long long)keys[j] << 32) |
                                  (unsigned)(4 * i + j);
                }
            }
        }
        __syncthreads();
        M = s_cnt; if (M > CAP) M = CAP;
        // reset hist for the candidate-hist pass
        for (int i = tid; i < NBIN; i += 1024) h[i] = 0u;
        if (tid == 0) s_cnt = 0;
        __syncthreads();
    }

    // ---- candidate hist (stream from global, L2-hot) ----
    for (int j = tid; j < M; j += 1024)
        atomicAdd(&h[bin_of((unsigned)(cb[j] >> 32))], 1u);
    __syncthreads();
    int t2 = rank_bin(h, wtot, &s_t, tid);

    // ---- survivors (bin >= t2) -> LDS; ~210 expected ----
    for (int j = tid; j < M; j += 1024) {
        unsigned long long p = cb[j];
        if (bin_of((unsigned)(p >> 32)) >= t2) {
            int q = atomicAdd(&s_cnt, 1);
            if (q < SVCAP) sv[q] = p;
        }
    }
    __syncthreads();
    int M2 = s_cnt; if (M2 > SVCAP) M2 = SVCAP;
    if (tid == 0) { sv[M2] = 0ull; sv[M2 + 1] = 0ull; }   // pad for b128 reads
    __syncthreads();

    // ---- exact rank by (key desc, idx desc): packed u64, b128 reads ----
    {
        int Mh = (M2 + 1) >> 1;
        const ulonglong2* v2 = (const ulonglong2*)sv;
        for (int j = tid; j < M2; j += 1024) {
            unsigned long long pj = sv[j];
            int rank = 0;
#pragma unroll 4
            for (int mm = 0; mm < Mh; ++mm) {
                ulonglong2 v = v2[mm];
                rank += (v.x > pj) + (v.y > pj);      // 0-pad never counts
            }
            if (rank < TOPK) sel[rank] = pj;
        }
    }
    __syncthreads();

    // ---- NMS-order re-rank: (key<<32)|~idx == (key desc, idx asc) ----
    if (tid < TOPK) {
        unsigned long long p = sel[tid];
        pk2[tid] = (p & 0xffffffff00000000ull) | (unsigned)(~(unsigned)p);
    }
    __syncthreads();
    if (tid < TOPK) {
        unsigned long long pj = pk2[tid];
        int r2 = 0;
        const ulonglong2* p2 = (const ulonglong2*)pk2;
#pragma unroll 4
        for (int mm = 0; mm < TOPK / 2; ++mm) {
            ulonglong2 v = p2[mm];
            r2 += (v.x > pj) + (v.y > pj);
        }
        int idx = (int)(~(unsigned)pj);
        nms_i[r2] = idx;
        nms_xy[r2] = make_float2(sg[2 * (size_t)idx], sg[2 * (size_t)idx + 1]);
    }
    __syncthreads();

    // ---- precompute kill matrix: krow[p] = 256-bit set of positions killed
    // when p wins (includes p itself). 16 waves x ballots, fully parallel. ----
    {
        int lane = tid & 63, wv = tid >> 6;
        for (int p = wv; p < TOPK; p += 16) {
            float2 w = nms_xy[p];
#pragma unroll
            for (int k = 0; k < 4; ++k) {
                int j = k * 64 + lane;
                float2 bj = nms_xy[j];
                bool kill = false;
                if (j < TOPK) {
                    if (j == p) kill = true;
                    else {
                        float inter = fminf(bj.y, w.y) - fmaxf(bj.x, w.x);
                        kill = inter > 0.f;
                    }
                }
                unsigned long long bm = __ballot(kill);
                if (lane == 0) krow[p][k] = bm;
            }
        }
    }
    __syncthreads();

    // ---- single-thread greedy scan: ffs + 4 independent b64 reads/iter ----
    if (tid == 0) {
        unsigned long long m0 = ~0ull, m1 = ~0ull, m2 = ~0ull, m3 = 0xffull;
        int* keep = out + b * TOPK;
        for (int it = 0; it < TOPK; ++it) {
            int p;
            if (m0)      p = __ffsll(m0) - 1;
            else if (m1) p = 64 + __ffsll(m1) - 1;
            else if (m2) p = 128 + __ffsll(m2) - 1;
            else if (m3) p = 192 + __ffsll(m3) - 1;
            else break;
            keep[it] = nms_i[p];
            m0 &= ~krow[p][0];
            m1 &= ~krow[p][1];
            m2 &= ~krow[p][2];
            m3 &= ~krow[p][3];
        }
    }
}

extern "C" void kernel_launch(void* const* d_in, const int* in_sizes, int n_in,
                              void* d_out, int out_size, void* d_ws, size_t ws_size,
                              hipStream_t stream) {
    const float* logits = (const float*)d_in[0];   // (8, 200000, 81) f32
    const float* segs   = (const float*)d_in[1];   // (8, 200000, 2)  f32
    int* out = (int*)d_out;                        // (16, 200) int32

    char* ws = (char*)d_ws;
    float*              scores = (float*)ws;                            // 6,400,000 B
    unsigned long long* cand   = (unsigned long long*)(ws + 6400000);   // 8*16384*8 = 1,048,576 B
    int*                cnt    = (int*)(ws + 6400000 + 1048576);        // 8 lines (1 KB)

    zero_kernel<<<1, 64, 0, stream>>>(cnt);
    dim3 sgrid(NN / 64, BB);                       // 3125 x 8
    scores_kernel<<<sgrid, 256, 0, stream>>>(logits, scores, cand, cnt);
    final_kernel<<<BB, 1024, 0, stream>>>(scores, segs, cand, cnt, out);
}